// Round 5
// baseline (73.674 us; speedup 1.0000x reference)
//
#include <hip/hip_runtime.h>
#include <hip/hip_bf16.h>

// C[M,N] = A[M,K] * B[K,N]; M=262144, K=N=128; fp32 in/out, bf16 MFMA.
// Memory-bound. Round-5 = round-4 experiment with the compile fix:
// __builtin_nontemporal_load needs ext_vector_type, not HIP_vector_type.
// L3 traffic shaping: NT loads for A (don't allocate in Infinity Cache),
// regular allocating stores for C (stay dirty-resident across replays).
// Kernel structure unchanged from round 3: pack_b packs embedding into bf16
// MFMA fragments; gemm: 8 waves/block, one LDS stage + one barrier, 2 tiles
// of 256 rows per block, grid=512.

typedef __bf16 bf16x8 __attribute__((ext_vector_type(8)));
typedef float  f32x16 __attribute__((ext_vector_type(16)));
typedef float  f32x4  __attribute__((ext_vector_type(4)));
typedef unsigned short ushortx8 __attribute__((ext_vector_type(8)));

#define M_TOTAL (64 * 4096)       // 262144 rows
#define KDIM 128
#define NDIM 128
#define TPB 512                   // 8 waves
#define BM 256                    // rows per tile (8 waves x 32 rows)
#define GRID 512                  // blocks; each does 2 tiles
#define TILES_PER_BLK 2

// Fragment (tile, lane, reg) holds B[k][n]:
//   n = (tile&3)*32 + (lane&31),  k = (tile>>2)*16 + (lane>>5)*8 + reg
__global__ __launch_bounds__(256) void pack_b_kernel(
    const float* __restrict__ Emb, ushortx8* __restrict__ Bp) {
  const int f    = blockIdx.x * 256 + threadIdx.x;   // 0..2047
  const int tile = f >> 6;
  const int lane = f & 63;
  const int n  = ((tile & 3) << 5) + (lane & 31);
  const int k0 = ((tile >> 2) << 4) + ((lane >> 5) << 3);
  ushortx8 frag;
#pragma unroll
  for (int r = 0; r < 8; ++r) {
    __bf16 h = (__bf16)Emb[(k0 + r) * NDIM + n];
    frag[r] = *(unsigned short*)&h;
  }
  Bp[f] = frag;
}

__device__ __forceinline__ bf16x8 cvt_frag(const f32x4 a0, const f32x4 a1) {
  bf16x8 af;
  af[0] = (__bf16)a0[0]; af[1] = (__bf16)a0[1];
  af[2] = (__bf16)a0[2]; af[3] = (__bf16)a0[3];
  af[4] = (__bf16)a1[0]; af[5] = (__bf16)a1[1];
  af[6] = (__bf16)a1[2]; af[7] = (__bf16)a1[3];
  return af;
}

__global__ __launch_bounds__(TPB) void emb_gemm_kernel(
    const float* __restrict__ A, const ushortx8* __restrict__ Bp,
    float* __restrict__ C) {
  __shared__ ushortx8 lds_b[2048];   // 32 KiB, linear fragment order

  const int tid = threadIdx.x;

  // ---- DMA-stage packed B -> LDS (linear, conflict-free, async) ----
#pragma unroll
  for (int i = 0; i < 4; ++i) {
    const int c = i * TPB + tid;
    __builtin_amdgcn_global_load_lds(
        (const __attribute__((address_space(1))) void*)(Bp + c),
        (__attribute__((address_space(3))) void*)(&lds_b[c]),
        16, 0, 0);
  }

  const int lane    = tid & 63;
  const int wave    = tid >> 6;            // 0..7
  const int colhalf = lane >> 5;
  const int koff    = colhalf * 8;         // k-offset within 16-wide k-step
  const bf16x8* bbase = (const bf16x8*)lds_b;

  // Prefetch tile 0 first-half A (kk=0..3); NT so A never allocates in L3.
  const int rbase = wave * 32 + (lane & 31);
  const float* ap0 = A + (size_t)(blockIdx.x * BM + rbase) * KDIM + koff;
  f32x4 apre[8];
#pragma unroll
  for (int kk = 0; kk < 4; ++kk) {
    apre[kk * 2]     = __builtin_nontemporal_load((const f32x4*)(ap0 + kk * 16));
    apre[kk * 2 + 1] = __builtin_nontemporal_load((const f32x4*)(ap0 + kk * 16 + 4));
  }

  __syncthreads();   // one barrier for the whole kernel: stage DMA complete

#pragma unroll 1
  for (int it = 0; it < TILES_PER_BLK; ++it) {
    const int mt  = blockIdx.x + it * GRID;          // tile index
    const int row0 = mt * BM + wave * 32;
    const float* ap = A + (size_t)(row0 + (lane & 31)) * KDIM + koff;

    f32x16 acc0 = {}, acc1 = {}, acc2 = {}, acc3 = {};

    // kk = 0..3 from prefetch regs
#pragma unroll
    for (int kk = 0; kk < 4; ++kk) {
      const bf16x8 af = cvt_frag(apre[kk * 2], apre[kk * 2 + 1]);
      const int tb = (kk * 4) * 64 + lane;
      acc0 = __builtin_amdgcn_mfma_f32_32x32x16_bf16(af, bbase[tb +   0], acc0, 0, 0, 0);
      acc1 = __builtin_amdgcn_mfma_f32_32x32x16_bf16(af, bbase[tb +  64], acc1, 0, 0, 0);
      acc2 = __builtin_amdgcn_mfma_f32_32x32x16_bf16(af, bbase[tb + 128], acc2, 0, 0, 0);
      acc3 = __builtin_amdgcn_mfma_f32_32x32x16_bf16(af, bbase[tb + 192], acc3, 0, 0, 0);
    }

    // kk = 4..7 loaded inline (NT)
#pragma unroll
    for (int kk = 4; kk < 8; ++kk) {
      const f32x4 a0 = __builtin_nontemporal_load((const f32x4*)(ap + kk * 16));
      const f32x4 a1 = __builtin_nontemporal_load((const f32x4*)(ap + kk * 16 + 4));
      const bf16x8 af = cvt_frag(a0, a1);
      const int tb = (kk * 4) * 64 + lane;
      acc0 = __builtin_amdgcn_mfma_f32_32x32x16_bf16(af, bbase[tb +   0], acc0, 0, 0, 0);
      acc1 = __builtin_amdgcn_mfma_f32_32x32x16_bf16(af, bbase[tb +  64], acc1, 0, 0, 0);
      acc2 = __builtin_amdgcn_mfma_f32_32x32x16_bf16(af, bbase[tb + 128], acc2, 0, 0, 0);
      acc3 = __builtin_amdgcn_mfma_f32_32x32x16_bf16(af, bbase[tb + 192], acc3, 0, 0, 0);
    }

    // Issue NEXT tile's first-half A loads now, overlapping the store drain.
    if (it + 1 < TILES_PER_BLK) {
      const float* apn = A + (size_t)((mt + GRID) * BM + rbase) * KDIM + koff;
#pragma unroll
      for (int kk = 0; kk < 4; ++kk) {
        apre[kk * 2]     = __builtin_nontemporal_load((const f32x4*)(apn + kk * 16));
        apre[kk * 2 + 1] = __builtin_nontemporal_load((const f32x4*)(apn + kk * 16 + 4));
      }
    }

    // C layout (32x32 MFMA): col = lane&31, row = (reg&3)+8*(reg>>2)+4*colhalf
    // REGULAR stores: allocate in L3 so C stays dirty-resident across replays.
    float* c0 = C + (size_t)row0 * NDIM + (lane & 31);
#pragma unroll
    for (int reg = 0; reg < 16; ++reg) {
      const int r = (reg & 3) + ((reg >> 2) << 3) + (colhalf << 2);
      float* cr = c0 + (size_t)r * NDIM;
      cr[0]  = acc0[reg];
      cr[32] = acc1[reg];
      cr[64] = acc2[reg];
      cr[96] = acc3[reg];
    }
  }
}

extern "C" void kernel_launch(void* const* d_in, const int* in_sizes, int n_in,
                              void* d_out, int out_size, void* d_ws, size_t ws_size,
                              hipStream_t stream) {
  const float* A   = (const float*)d_in[0];   // inputs  (B,S,I) fp32
  const float* Emb = (const float*)d_in[1];   // embedding (I,E) fp32
  float* out = (float*)d_out;                 // (B,S,E) fp32
  ushortx8* Bp = (ushortx8*)d_ws;             // 32 KiB packed B fragments

  pack_b_kernel<<<dim3(8), dim3(256), 0, stream>>>(Emb, Bp);
  emb_gemm_kernel<<<dim3(GRID), dim3(TPB), 0, stream>>>(A, Bp, out);
}